// Round 6
// baseline (96.181 us; speedup 1.0000x reference)
//
#include <hip/hip_runtime.h>

#define B_    32
#define N_    10000
#define G_    256
#define HID_  256
#define EPS_  1e-5f

// prep_k grid segmentation
#define TB_W1  2504            // 313 col-tiles x 8 row-tiles (W1: 256 x 10000)
#define TB_X   313             // x: 32 x 10000
#define TB_W2  64              // W2: 256 x 256
#define NB_CMP 256             // mask compaction, one block per g
#define PREP_GRID (TB_W1 + TB_X + TB_W2 + NB_CMP)   // 3137

#define DKB_  40               // dense-group split-K producer blocks
#define DCH_  250              // genes per dense chunk (40*250 = 10000)

// ---------------------------------------------------------------------------
// Tiled transpose helper: src R x C row-major -> dst C x R row-major.
// ---------------------------------------------------------------------------
__device__ inline void transpose_tile(const float* __restrict__ src,
                                      float* __restrict__ dst,
                                      int R, int C, int bx, int by, int t,
                                      float (*tile)[33]) {
    int tx = t & 31, ty = t >> 5;      // 32 x 8
    int c0 = bx * 32, r0 = by * 32;
#pragma unroll
    for (int j = 0; j < 4; ++j) {
        int r = r0 + ty + j * 8, c = c0 + tx;
        if (r < R && c < C) tile[ty + j * 8][tx] = src[(size_t)r * C + c];
    }
    __syncthreads();
#pragma unroll
    for (int j = 0; j < 4; ++j) {
        int c = c0 + ty + j * 8, r = r0 + tx;
        if (r < R && c < C) dst[(size_t)c * R + r] = tile[tx][ty + j * 8];
    }
}

// ---------------------------------------------------------------------------
// Fused prep: W1/x/W2 transposes + mask compaction + done-counter reset.
// ---------------------------------------------------------------------------
__global__ __launch_bounds__(256) void prep_k(const float* __restrict__ W1,
                                              const float* __restrict__ x,
                                              const float* __restrict__ W2,
                                              const float* __restrict__ mask,
                                              float* __restrict__ w1t,
                                              float* __restrict__ xt,
                                              float* __restrict__ w2t,
                                              int* __restrict__ cnt,
                                              unsigned short* __restrict__ idx,
                                              int* __restrict__ ctr) {
    __shared__ float tile[32][33];
    __shared__ int c;
    int bid = blockIdx.x, t = threadIdx.x;

    if (bid == 0 && t == 0) *ctr = 0;   // reset mega_k's producer counter

    if (bid < TB_W1) {
        transpose_tile(W1, w1t, HID_, N_, bid % 313, bid / 313, t, tile);
    } else if (bid < TB_W1 + TB_X) {
        transpose_tile(x, xt, B_, N_, bid - TB_W1, 0, t, tile);
    } else if (bid < TB_W1 + TB_X + TB_W2) {
        int b = bid - (TB_W1 + TB_X);
        transpose_tile(W2, w2t, 256, HID_, b % 8, b / 8, t, tile);
    } else {
        int g = bid - (TB_W1 + TB_X + TB_W2);
        if (t == 0) c = 0;
        __syncthreads();
        for (int n = t; n < N_; n += 256) {
            if (mask[(size_t)g * N_ + n] != 0.0f) {
                int p = atomicAdd(&c, 1);          // LDS atomic only
                idx[(size_t)g * N_ + p] = (unsigned short)n;
            }
        }
        __syncthreads();
        if (t == 0) cnt[g] = c;
    }
}

// ---------------------------------------------------------------------------
// MEGA kernel: one launch for GEMM1 + BN1 + ReLU + GEMM2 + BN2 + ReLU.
//   bid <  40 : dense split-K producer (group 255 chunk) -> hpartD, release++
//   bid 40..294: sparse group g = bid-40, fully fused in-block
//   bid == 295: group-255 consumer: acquire-spin, reduce partials, fused path
// 512 threads: tc = t&63 (float4 column; wave spans full 1KB row, coalesced),
//              tb = t>>6 (rows/batches 4tb..4tb+3; wave-uniform broadcasts).
// Grid (296 blocks, 33KB LDS, 8 waves) is fully co-resident -> spin is safe.
// ---------------------------------------------------------------------------
__global__ __launch_bounds__(512) void mega_k(const float4* __restrict__ w1t4,
                                              const float4* __restrict__ xt4,
                                              const int* __restrict__ cnt,
                                              const unsigned short* __restrict__ idx,
                                              const float4* __restrict__ b1_4,
                                              const float* __restrict__ g1,
                                              const float* __restrict__ be1,
                                              const float4* __restrict__ w2t4,
                                              const float4* __restrict__ b2_4,
                                              const float* __restrict__ g2,
                                              const float* __restrict__ be2,
                                              float4* __restrict__ hpartD,
                                              int* __restrict__ ctr,
                                              float4* __restrict__ z4) {
    // xs/ns (phase A) and lh (phases B/C) are phase-disjoint: overlay them.
    __shared__ __align__(16) char smem[33280];
    __shared__ float rs[8], rss[8];
    int* ns = (int*)smem;                              // 512 B
    float4 (*xs)[9] = (float4 (*)[9])(smem + 512);     // 128 x 9 x 16 B
    float (*lh)[260] = (float (*)[260])smem;           // 32 x 260 x 4 B

    const int bid = blockIdx.x, t = threadIdx.x;
    const int tc = t & 63;             // float4 column 0..63
    const int tb = t >> 6;             // wave id = row group (rows 4tb..4tb+3)

    float4 acc[4];
    acc[0] = make_float4(0.f, 0.f, 0.f, 0.f);
    acc[1] = acc[0]; acc[2] = acc[0]; acc[3] = acc[0];

    const bool producer = (bid < DKB_);
    const int g = producer ? 255 : bid - DKB_;

    if (producer || g < 255) {
        // ---------------- phase A: GEMM1 accumulation ----------------
        int k0, kend;
        if (producer) { k0 = bid * DCH_; kend = k0 + DCH_; }
        else          { k0 = 0;          kend = cnt[g];    }

        for (int base = k0; base < kend; base += 128) {
            int kn = min(128, kend - base);
            __syncthreads();                        // protect ns/xs reuse
            if (!producer && t < kn) ns[t] = idx[(size_t)g * N_ + base + t];
            __syncthreads();
            for (int i = t; i < kn * 8; i += 512) {
                int k = i >> 3, q = i & 7;
                int n = producer ? (base + k) : ns[k];
                xs[k][q] = xt4[(size_t)n * 8 + q];
            }
            __syncthreads();

#pragma unroll 4
            for (int k = 0; k < kn; ++k) {
                int n = producer ? (base + k) : ns[k];
                float4 wv = w1t4[(size_t)n * 64 + tc];   // 1KB/wave, coalesced
                float4 xv = xs[k][tb];                    // LDS broadcast
                acc[0].x = fmaf(xv.x, wv.x, acc[0].x);
                acc[0].y = fmaf(xv.x, wv.y, acc[0].y);
                acc[0].z = fmaf(xv.x, wv.z, acc[0].z);
                acc[0].w = fmaf(xv.x, wv.w, acc[0].w);
                acc[1].x = fmaf(xv.y, wv.x, acc[1].x);
                acc[1].y = fmaf(xv.y, wv.y, acc[1].y);
                acc[1].z = fmaf(xv.y, wv.z, acc[1].z);
                acc[1].w = fmaf(xv.y, wv.w, acc[1].w);
                acc[2].x = fmaf(xv.z, wv.x, acc[2].x);
                acc[2].y = fmaf(xv.z, wv.y, acc[2].y);
                acc[2].z = fmaf(xv.z, wv.z, acc[2].z);
                acc[2].w = fmaf(xv.z, wv.w, acc[2].w);
                acc[3].x = fmaf(xv.w, wv.x, acc[3].x);
                acc[3].y = fmaf(xv.w, wv.y, acc[3].y);
                acc[3].z = fmaf(xv.w, wv.z, acc[3].z);
                acc[3].w = fmaf(xv.w, wv.w, acc[3].w);
            }
        }

        if (producer) {
            float4* dst = hpartD + (size_t)bid * 2048;
            dst[(4 * tb + 0) * 64 + tc] = acc[0];
            dst[(4 * tb + 1) * 64 + tc] = acc[1];
            dst[(4 * tb + 2) * 64 + tc] = acc[2];
            dst[(4 * tb + 3) * 64 + tc] = acc[3];
            __threadfence();                 // make partials device-visible
            __syncthreads();                 // all threads' stores fenced
            if (t == 0)
                __hip_atomic_fetch_add(ctr, 1, __ATOMIC_RELEASE,
                                       __HIP_MEMORY_SCOPE_AGENT);
            return;
        }
        // sparse group: + b1
        {
            float4 bb = b1_4[tc];
#pragma unroll
            for (int j = 0; j < 4; ++j) {
                acc[j].x += bb.x; acc[j].y += bb.y;
                acc[j].z += bb.z; acc[j].w += bb.w;
            }
        }
        __syncthreads();   // all xs reads done before lh overlays smem
    } else {
        // ---------------- group-255 consumer: reduce partials ----------------
        if (t == 0) {
            while (__hip_atomic_load(ctr, __ATOMIC_ACQUIRE,
                                     __HIP_MEMORY_SCOPE_AGENT) < DKB_) {}
            __threadfence();
        }
        __syncthreads();
        float4 bb = b1_4[tc];
#pragma unroll
        for (int j = 0; j < 4; ++j) acc[j] = bb;
#pragma unroll 4
        for (int kb = 0; kb < DKB_; ++kb) {
            const float4* pp = hpartD + (size_t)kb * 2048 + (4 * tb) * 64 + tc;
            float4 v0 = pp[0], v1 = pp[64], v2 = pp[128], v3 = pp[192];
            acc[0].x += v0.x; acc[0].y += v0.y; acc[0].z += v0.z; acc[0].w += v0.w;
            acc[1].x += v1.x; acc[1].y += v1.y; acc[1].z += v1.z; acc[1].w += v1.w;
            acc[2].x += v2.x; acc[2].y += v2.y; acc[2].z += v2.z; acc[2].w += v2.w;
            acc[3].x += v3.x; acc[3].y += v3.y; acc[3].z += v3.z; acc[3].w += v3.w;
        }
    }

    // ---------------- phase B: BN1 stats (from registers) ----------------
    float s = 0.f, ss = 0.f;
#pragma unroll
    for (int j = 0; j < 4; ++j) {
        s  += acc[j].x + acc[j].y + acc[j].z + acc[j].w;
        ss += acc[j].x * acc[j].x + acc[j].y * acc[j].y
            + acc[j].z * acc[j].z + acc[j].w * acc[j].w;
    }
#pragma unroll
    for (int o = 32; o > 0; o >>= 1) { s += __shfl_down(s, o); ss += __shfl_down(ss, o); }
    if (tc == 0) { rs[tb] = s; rss[tb] = ss; }
    __syncthreads();
    float S = 0.f, SS = 0.f;
#pragma unroll
    for (int j = 0; j < 8; ++j) { S += rs[j]; SS += rss[j]; }
    const float inv = 1.0f / (float)(B_ * HID_);
    float mean = S * inv;
    float var  = SS * inv - mean * mean;       // biased, matches jnp.var
    float sc = g1[g] * rsqrtf(var + EPS_);
    float sh = be1[g] - mean * sc;

    // normalize + ReLU own elements -> LDS
#pragma unroll
    for (int j = 0; j < 4; ++j) {
        float4 v;
        v.x = fmaxf(fmaf(acc[j].x, sc, sh), 0.f);
        v.y = fmaxf(fmaf(acc[j].y, sc, sh), 0.f);
        v.z = fmaxf(fmaf(acc[j].z, sc, sh), 0.f);
        v.w = fmaxf(fmaf(acc[j].w, sc, sh), 0.f);
        *(float4*)&lh[4 * tb + j][4 * tc] = v;
    }
    __syncthreads();

    // ---------------- phase C: GEMM2 + BN2 + ReLU ----------------
    float4 bb2 = b2_4[tc];
    float4 a2[4] = {bb2, bb2, bb2, bb2};
#pragma unroll 8
    for (int k = 0; k < HID_; ++k) {
        float4 wv = w2t4[(size_t)k * 64 + tc];         // 1KB/wave, coalesced
#pragma unroll
        for (int j = 0; j < 4; ++j) {
            float xv = lh[4 * tb + j][k];              // LDS broadcast
            a2[j].x = fmaf(xv, wv.x, a2[j].x);
            a2[j].y = fmaf(xv, wv.y, a2[j].y);
            a2[j].z = fmaf(xv, wv.z, a2[j].z);
            a2[j].w = fmaf(xv, wv.w, a2[j].w);
        }
    }

    s = 0.f; ss = 0.f;
#pragma unroll
    for (int j = 0; j < 4; ++j) {
        s  += a2[j].x + a2[j].y + a2[j].z + a2[j].w;
        ss += a2[j].x * a2[j].x + a2[j].y * a2[j].y
            + a2[j].z * a2[j].z + a2[j].w * a2[j].w;
    }
#pragma unroll
    for (int o = 32; o > 0; o >>= 1) { s += __shfl_down(s, o); ss += __shfl_down(ss, o); }
    if (tc == 0) { rs[tb] = s; rss[tb] = ss; }   // safe: BN1 reads were pre-barrier
    __syncthreads();
    S = 0.f; SS = 0.f;
#pragma unroll
    for (int j = 0; j < 8; ++j) { S += rs[j]; SS += rss[j]; }
    mean = S * inv;
    var  = SS * inv - mean * mean;
    float sc2 = g2[g] * rsqrtf(var + EPS_);
    float sh2 = be2[g] - mean * sc2;

#pragma unroll
    for (int j = 0; j < 4; ++j) {
        int b = 4 * tb + j;
        float4 v;
        v.x = fmaxf(fmaf(a2[j].x, sc2, sh2), 0.f);
        v.y = fmaxf(fmaf(a2[j].y, sc2, sh2), 0.f);
        v.z = fmaxf(fmaf(a2[j].z, sc2, sh2), 0.f);
        v.w = fmaxf(fmaf(a2[j].w, sc2, sh2), 0.f);
        z4[(size_t)(b * G_ + g) * 64 + tc] = v;
    }
}

// ---------------------------------------------------------------------------
extern "C" void kernel_launch(void* const* d_in, const int* in_sizes, int n_in,
                              void* d_out, int out_size, void* d_ws, size_t ws_size,
                              hipStream_t stream) {
    const float* x    = (const float*)d_in[0];
    const float* mask = (const float*)d_in[1];
    const float* W1   = (const float*)d_in[2];
    const float* b1   = (const float*)d_in[3];
    const float* g1   = (const float*)d_in[4];
    const float* be1  = (const float*)d_in[5];
    const float* W2   = (const float*)d_in[6];
    const float* b2   = (const float*)d_in[7];
    const float* g2   = (const float*)d_in[8];
    const float* be2  = (const float*)d_in[9];
    float* out = (float*)d_out;

    char* ws = (char*)d_ws;
    size_t off = 0;
    auto take = [&](size_t bytes) {
        char* p = ws + off;
        off = (off + bytes + 255) & ~(size_t)255;
        return p;
    };
    float* w1t          = (float*)take((size_t)N_ * HID_ * 4);       // (N, HID)
    float* xt           = (float*)take((size_t)N_ * B_ * 4);         // (N, B)
    float* w2t          = (float*)take((size_t)HID_ * HID_ * 4);     // (HID, Z)
    float* hpartD       = (float*)take((size_t)DKB_ * B_ * HID_ * 4);
    int* cnt            = (int*)take((size_t)G_ * 4);
    unsigned short* idx = (unsigned short*)take((size_t)G_ * N_ * 2);
    int* ctr            = (int*)take(256);

    prep_k<<<PREP_GRID, 256, 0, stream>>>(W1, x, W2, mask, w1t, xt, w2t, cnt, idx, ctr);
    mega_k<<<DKB_ + G_, 512, 0, stream>>>((const float4*)w1t, (const float4*)xt,
                                          cnt, idx, (const float4*)b1,
                                          g1, be1,
                                          (const float4*)w2t, (const float4*)b2,
                                          g2, be2,
                                          (float4*)hpartD, ctr, (float4*)out);
}